// Round 2
// baseline (600.731 us; speedup 1.0000x reference)
//
#include <hip/hip_runtime.h>
#include <hip/hip_bf16.h>
#include <math.h>

#define N_NODES 65536
#define NDIR 9
#define NEDGE 589824

typedef __attribute__((ext_vector_type(8))) short short8;
typedef __attribute__((ext_vector_type(4))) float f32x4;

__device__ inline float bf2f(unsigned short u){ return __uint_as_float(((unsigned int)u)<<16); }
__device__ inline unsigned short f2bf(float f){
  unsigned int x = __float_as_uint(f);
  x += 0x7fff + ((x>>16)&1);           // round-to-nearest-even
  return (unsigned short)(x>>16);
}
__device__ inline float elu1(float x){ return x>0.f ? x : expm1f(x); }

// ---- prep: fold BN scale into W, transpose to [n][k] bf16 ----
__global__ void prep_w(const float* __restrict__ W1, const float* __restrict__ W2,
                       const float* __restrict__ W3,
                       const float* __restrict__ g1, const float* __restrict__ rv1,
                       const float* __restrict__ g2, const float* __restrict__ rv2,
                       const float* __restrict__ g3, const float* __restrict__ rv3,
                       unsigned short* __restrict__ Wt1, unsigned short* __restrict__ Wt2){
  int idx = blockIdx.x*256 + threadIdx.x;
  const float eps = 1e-5f;
  if (idx < 1280*128) {
    int n = idx >> 7, k = idx & 127;
    float v;
    if (n < 1152) { int d = n >> 7, c = n & 127;
      float s = g1[c]*rsqrtf(rv1[c]+eps); v = W1[(d*128 + k)*128 + c] * s; }
    else { int c = n - 1152;
      float s = g3[c]*rsqrtf(rv3[c]+eps); v = W3[k*128 + c] * s; }
    Wt1[idx] = f2bf(v);
  } else {
    int j = idx - 1280*128;
    int n = j >> 7, k = j & 127;
    int d = n >> 7, c = n & 127;
    float s = g2[c]*rsqrtf(rv2[c]+eps);
    Wt2[j] = f2bf(W2[(d*128 + k)*128 + c] * s);
  }
}

__global__ void prep_bias(const float* b1,const float* g1,const float* be1,const float* rm1,const float* rv1,
                          const float* b2,const float* g2,const float* be2,const float* rm2,const float* rv2,
                          const float* b3,const float* g3,const float* be3,const float* rm3,const float* rv3,
                          float* bias1, float* bias2, float* bias3, float* s3v){
  int c = threadIdx.x;
  const float eps = 1e-5f;
  float s1 = g1[c]*rsqrtf(rv1[c]+eps);
  bias1[c] = (b1[c]-rm1[c])*s1 + be1[c];
  float s2 = g2[c]*rsqrtf(rv2[c]+eps);
  bias2[c] = (b2[c]-rm2[c])*s2 + be2[c];
  float s3 = g3[c]*rsqrtf(rv3[c]+eps);
  bias3[c] = (b3[c]-rm3[c])*s3 + be3[c];
  s3v[c] = s3;
}

// ---- cast x to bf16 once (halves GEMM1 A traffic, unifies GEMM path) ----
__global__ void xcast_k(const float* __restrict__ x, unsigned short* __restrict__ xb){
  int i = (blockIdx.x*256 + threadIdx.x)*8;
  f32x4 f0 = *(const f32x4*)(x + i);
  f32x4 f1 = *(const f32x4*)(x + i + 4);
  short8 t;
  #pragma unroll
  for (int j = 0; j < 4; j++){ t[j] = (short)f2bf(f0[j]); t[4+j] = (short)f2bf(f1[j]); }
  *(short8*)(xb + i) = t;
}

// ---- CSR build: hist -> scan -> scatter ----
__global__ void hist_k(const int* __restrict__ dst, int* __restrict__ hist){
  int e = blockIdx.x*256 + threadIdx.x;
  atomicAdd(&hist[dst[e]], 1);
}

__global__ void scan1_k(const int* __restrict__ hist, int* __restrict__ rs, int* __restrict__ bsum){
  __shared__ int wsum[4];
  int t = threadIdx.x;
  int base = blockIdx.x*1024 + t*4;
  int4 v = *(const int4*)(hist + base);
  int s = v.x + v.y + v.z + v.w;
  int lane = t & 63, w = t >> 6;
  int inc = s;
  #pragma unroll
  for (int o = 1; o < 64; o <<= 1){ int n = __shfl_up(inc, o); if (lane >= o) inc += n; }
  if (lane == 63) wsum[w] = inc;
  __syncthreads();
  int acc = 0;
  for (int i = 0; i < w; i++) acc += wsum[i];
  int ex = acc + inc - s;
  rs[base] = ex; rs[base+1] = ex + v.x; rs[base+2] = ex + v.x + v.y; rs[base+3] = ex + v.x + v.y + v.z;
  if (t == 255) bsum[blockIdx.x] = acc + inc;
}

__global__ void scan2_k(int* bsum){
  int lane = threadIdx.x;
  int v = bsum[lane], inc = v;
  #pragma unroll
  for (int o = 1; o < 64; o <<= 1){ int n = __shfl_up(inc, o); if (lane >= o) inc += n; }
  bsum[lane] = inc - v;
}

__global__ void scan3_k(int* rs, const int* bsum, int* cursor){
  int i = blockIdx.x*256 + threadIdx.x;
  int v = rs[i] + bsum[i >> 10];
  rs[i] = v; cursor[i] = v;
}

__global__ void scatter_k(const int* __restrict__ src, const int* __restrict__ dst,
                          const int* __restrict__ sel,
                          int* __restrict__ cursor, int* __restrict__ sorted){
  int e = blockIdx.x*256 + threadIdx.x;
  int d = dst[e];
  int pos = atomicAdd(&cursor[d], 1);
  sorted[pos] = (src[e] << 4) | sel[e];
}

// ---- GEMM: [65536,128]bf16 @ Wt[ncols,128]^T -> C[n][col] bf16 ----
// grid = (512 m-tiles, 5 nt-pairs). Occupancy: VGPR~104 & LDS 34KB both give
// 4 blocks/CU resident; grid.y split supplies 10 blocks/CU so 4 stay resident
// (R1 had only 2 -> 21% occupancy, latency-bound, MfmaUtil 8.5%).
__global__ __launch_bounds__(256) void gemm_k(const unsigned short* __restrict__ A,
                       const unsigned short* __restrict__ Wt,
                       unsigned short* __restrict__ C, int ntiles, int ostride){
  __shared__ unsigned short stg[128*136];   // repack buffer, rows padded to 272B
  int w = threadIdx.x >> 6, lane = threadIdx.x & 63;
  int q = lane >> 4, r = lane & 15;
  int m0 = blockIdx.x * 128;
  int nt0 = blockIdx.y * 2;
  int ntE = nt0 + 2 > ntiles ? ntiles : nt0 + 2;

  short8 a[2][4];                            // hoisted A-frags: K=128 in regs
  #pragma unroll
  for (int ms = 0; ms < 2; ms++){
    int row = m0 + w*32 + ms*16 + r;
    #pragma unroll
    for (int kk = 0; kk < 4; kk++)
      a[ms][kk] = *(const short8*)(A + (size_t)row*128 + kk*32 + q*8);
  }

  for (int nt = nt0; nt < ntE; nt++){
    f32x4 acc[2][8];
    #pragma unroll
    for (int ms = 0; ms < 2; ms++)
      #pragma unroll
      for (int ns = 0; ns < 8; ns++) acc[ms][ns] = (f32x4){0.f,0.f,0.f,0.f};

    #pragma unroll
    for (int kk = 0; kk < 4; kk++){
      short8 b[8];
      #pragma unroll
      for (int ns = 0; ns < 8; ns++){
        const unsigned short* p = Wt + (size_t)(nt*128 + ns*16 + r)*128 + kk*32 + q*8;
        b[ns] = *(const short8*)p;
      }
      #pragma unroll
      for (int ns = 0; ns < 8; ns++)
        #pragma unroll
        for (int ms = 0; ms < 2; ms++)
          acc[ms][ns] = __builtin_amdgcn_mfma_f32_16x16x32_bf16(a[ms][kk], b[ns], acc[ms][ns], 0, 0, 0);
    }

    // repack via LDS: each wave writes/reads only its own 32 rows -> no barrier
    #pragma unroll
    for (int ms = 0; ms < 2; ms++)
      #pragma unroll
      for (int ns = 0; ns < 8; ns++)
        #pragma unroll
        for (int rr = 0; rr < 4; rr++){
          int row = w*32 + ms*16 + q*4 + rr;
          int col = ns*16 + r;
          stg[row*136 + col] = f2bf(acc[ms][ns][rr]);
        }
    #pragma unroll
    for (int i = 0; i < 8; i++){
      int idx = i*64 + lane;            // 512 chunks of 16B = 32 rows x 256B
      int row = idx >> 4;
      int within = idx & 15;
      short8 vv = *(const short8*)&stg[(w*32 + row)*136 + within*8];
      int grow = m0 + w*32 + row;
      *(short8*)(C + (size_t)grow*ostride + nt*128 + within*8) = vv;
    }
  }
}

// ---- gather layer 1: sum Y rows per dst, +bias1, ELU -> h1 bf16 ----
__global__ void gather1_k(const unsigned short* __restrict__ Y, const int* __restrict__ rs,
                          const int* __restrict__ cur, const int* __restrict__ sorted,
                          const float* __restrict__ bias1, unsigned short* __restrict__ h1){
  int node = blockIdx.x*4 + (threadIdx.x >> 6);
  int lane = threadIdx.x & 63;
  int s = rs[node], e = cur[node];
  float a0 = 0.f, a1 = 0.f;
  int pk = (s < e) ? sorted[s] : 0;
  for (int i = s; i < e; i++){
    int nx = (i+1 < e) ? sorted[i+1] : 0;   // prefetch next edge key
    const unsigned short* p = Y + (size_t)(pk >> 4)*1280 + (pk & 15)*128 + lane*2;
    unsigned int v = *(const unsigned int*)p;
    a0 += bf2f((unsigned short)(v & 0xffff));
    a1 += bf2f((unsigned short)(v >> 16));
    pk = nx;
  }
  float2 bb = *(const float2*)(bias1 + lane*2);
  a0 = elu1(a0 + bb.x); a1 = elu1(a1 + bb.y);
  unsigned int pk2 = (unsigned int)f2bf(a0) | ((unsigned int)f2bf(a1) << 16);
  *(unsigned int*)(h1 + (size_t)node*128 + lane*2) = pk2;
}

// ---- gather layer 2 + shortcut + BN2/ELU/BN3/ELU -> fp32 out ----
__global__ void gather2_k(const unsigned short* __restrict__ Y, const int* __restrict__ rs,
                          const int* __restrict__ cur, const int* __restrict__ sorted,
                          const float* __restrict__ bias2, const float* __restrict__ bias3,
                          const float* __restrict__ s3v, float* __restrict__ out){
  int node = blockIdx.x*4 + (threadIdx.x >> 6);
  int lane = threadIdx.x & 63;
  int s = rs[node], e = cur[node];
  float a0 = 0.f, a1 = 0.f, c0 = 0.f, c1 = 0.f;
  int pk = (s < e) ? sorted[s] : 0;
  for (int i = s; i < e; i++){
    int nx = (i+1 < e) ? sorted[i+1] : 0;
    int srcn = pk >> 4, sl = pk & 15;
    const unsigned short* base = Y + (size_t)srcn*1280;
    unsigned int v = *(const unsigned int*)(base + sl*128 + lane*2);
    a0 += bf2f((unsigned short)(v & 0xffff));
    a1 += bf2f((unsigned short)(v >> 16));
    if (sl == 0){
      unsigned int u = *(const unsigned int*)(base + 1152 + lane*2);
      c0 += bf2f((unsigned short)(u & 0xffff));
      c1 += bf2f((unsigned short)(u >> 16));
    }
    pk = nx;
  }
  float2 b2 = *(const float2*)(bias2 + lane*2);
  float2 b3 = *(const float2*)(bias3 + lane*2);
  float2 s3 = *(const float2*)(s3v + lane*2);
  float h0 = elu1(a0 + b2.x), h1v = elu1(a1 + b2.y);
  float o0 = elu1(h0*s3.x + c0 + b3.x);
  float o1 = elu1(h1v*s3.y + c1 + b3.y);
  float2 o = {o0, o1};
  *(float2*)(out + (size_t)node*128 + lane*2) = o;
}

extern "C" void kernel_launch(void* const* d_in, const int* in_sizes, int n_in,
                              void* d_out, int out_size, void* d_ws, size_t ws_size,
                              hipStream_t stream){
  const float* x   = (const float*)d_in[0];
  const int*   ei  = (const int*)d_in[1];
  const int*   sel = (const int*)d_in[2];
  const float* W1  = (const float*)d_in[3];
  const float* b1  = (const float*)d_in[4];
  const float* g1  = (const float*)d_in[5];
  const float* be1 = (const float*)d_in[6];
  const float* rm1 = (const float*)d_in[7];
  const float* rv1 = (const float*)d_in[8];
  const float* W2  = (const float*)d_in[9];
  const float* b2  = (const float*)d_in[10];
  const float* g2  = (const float*)d_in[11];
  const float* be2 = (const float*)d_in[12];
  const float* rm2 = (const float*)d_in[13];
  const float* rv2 = (const float*)d_in[14];
  const float* W3  = (const float*)d_in[15];
  const float* b3  = (const float*)d_in[16];
  const float* g3  = (const float*)d_in[17];
  const float* be3 = (const float*)d_in[18];
  const float* rm3 = (const float*)d_in[19];
  const float* rv3 = (const float*)d_in[20];

  char* ws = (char*)d_ws;
  unsigned short* Y    = (unsigned short*)(ws);                   // [65536][1280] bf16: cols 0..1151 = dirs (Y1 then Y2), 1152..1279 = Y3
  unsigned short* h1   = (unsigned short*)(ws + 167772160);       // [65536][128] bf16; ALSO aliased as xb (dead before gather1 writes it)
  unsigned short* Wt1  = (unsigned short*)(ws + 184549376);       // [1280][128] bf16
  unsigned short* Wt2  = (unsigned short*)(ws + 184877056);       // [1152][128] bf16
  float* bias1  = (float*)(ws + 185171968);
  float* bias2  = bias1 + 128;
  float* bias3  = bias1 + 256;
  float* s3v    = bias1 + 384;
  int* hist     = (int*)(ws + 185174016);
  int* rs       = (int*)(ws + 185436160);
  int* cursor   = (int*)(ws + 185698304);
  int* bsum     = (int*)(ws + 185960448);
  int* sorted   = (int*)(ws + 185960704);                         // end: 188,320,000 bytes
  unsigned short* xb = h1;                                        // alias: xb live only until GEMM1 done

  const int* srcp = ei;
  const int* dstp = ei + NEDGE;

  hipMemsetAsync(hist, 0, N_NODES*sizeof(int), stream);
  prep_w<<<1216, 256, 0, stream>>>(W1, W2, W3, g1, rv1, g2, rv2, g3, rv3, Wt1, Wt2);
  prep_bias<<<1, 128, 0, stream>>>(b1,g1,be1,rm1,rv1, b2,g2,be2,rm2,rv2, b3,g3,be3,rm3,rv3,
                                   bias1, bias2, bias3, s3v);
  xcast_k<<<4096, 256, 0, stream>>>(x, xb);
  hist_k<<<NEDGE/256, 256, 0, stream>>>(dstp, hist);
  scan1_k<<<64, 256, 0, stream>>>(hist, rs, bsum);
  scan2_k<<<1, 64, 0, stream>>>(bsum);
  scan3_k<<<256, 256, 0, stream>>>(rs, bsum, cursor);
  scatter_k<<<NEDGE/256, 256, 0, stream>>>(srcp, dstp, sel, cursor, sorted);

  gemm_k<<<dim3(512,5), 256, 0, stream>>>(xb, Wt1, Y, 10, 1280);       // Y1 (9 dirs) + Y3
  gather1_k<<<16384, 256, 0, stream>>>(Y, rs, cursor, sorted, bias1, h1);
  gemm_k<<<dim3(512,5), 256, 0, stream>>>(h1, Wt2, Y, 9, 1280);        // Y2 overwrites dir cols, keeps Y3
  gather2_k<<<16384, 256, 0, stream>>>(Y, rs, cursor, sorted, bias2, bias3, s3v, (float*)d_out);
}

// Round 3
// 455.827 us; speedup vs baseline: 1.3179x; 1.3179x over previous
//
#include <hip/hip_runtime.h>
#include <hip/hip_bf16.h>
#include <math.h>

#define N_NODES 65536
#define NDIR 9
#define NEDGE 589824

typedef __attribute__((ext_vector_type(8))) short short8;
typedef __attribute__((ext_vector_type(4))) float f32x4;

__device__ inline float bf2f(unsigned short u){ return __uint_as_float(((unsigned int)u)<<16); }
__device__ inline unsigned short f2bf(float f){
  unsigned int x = __float_as_uint(f);
  x += 0x7fff + ((x>>16)&1);           // round-to-nearest-even
  return (unsigned short)(x>>16);
}
__device__ inline float elu1(float x){ return x>0.f ? x : expm1f(x); }

// ---- prep: fold BN scale into W, transpose to [n][k] bf16 ----
__global__ void prep_w(const float* __restrict__ W1, const float* __restrict__ W2,
                       const float* __restrict__ W3,
                       const float* __restrict__ g1, const float* __restrict__ rv1,
                       const float* __restrict__ g2, const float* __restrict__ rv2,
                       const float* __restrict__ g3, const float* __restrict__ rv3,
                       unsigned short* __restrict__ Wt1, unsigned short* __restrict__ Wt2){
  int idx = blockIdx.x*256 + threadIdx.x;
  const float eps = 1e-5f;
  if (idx < 1280*128) {
    int n = idx >> 7, k = idx & 127;
    float v;
    if (n < 1152) { int d = n >> 7, c = n & 127;
      float s = g1[c]*rsqrtf(rv1[c]+eps); v = W1[(d*128 + k)*128 + c] * s; }
    else { int c = n - 1152;
      float s = g3[c]*rsqrtf(rv3[c]+eps); v = W3[k*128 + c] * s; }
    Wt1[idx] = f2bf(v);
  } else {
    int j = idx - 1280*128;
    int n = j >> 7, k = j & 127;
    int d = n >> 7, c = n & 127;
    float s = g2[c]*rsqrtf(rv2[c]+eps);
    Wt2[j] = f2bf(W2[(d*128 + k)*128 + c] * s);
  }
}

__global__ void prep_bias(const float* b1,const float* g1,const float* be1,const float* rm1,const float* rv1,
                          const float* b2,const float* g2,const float* be2,const float* rm2,const float* rv2,
                          const float* b3,const float* g3,const float* be3,const float* rm3,const float* rv3,
                          float* bias1, float* bias2, float* bias3, float* s3v){
  int c = threadIdx.x;
  const float eps = 1e-5f;
  float s1 = g1[c]*rsqrtf(rv1[c]+eps);
  bias1[c] = (b1[c]-rm1[c])*s1 + be1[c];
  float s2 = g2[c]*rsqrtf(rv2[c]+eps);
  bias2[c] = (b2[c]-rm2[c])*s2 + be2[c];
  float s3 = g3[c]*rsqrtf(rv3[c]+eps);
  bias3[c] = (b3[c]-rm3[c])*s3 + be3[c];
  s3v[c] = s3;
}

// ---- cast x to bf16 once ----
__global__ void xcast_k(const float* __restrict__ x, unsigned short* __restrict__ xb){
  int i = (blockIdx.x*256 + threadIdx.x)*8;
  f32x4 f0 = *(const f32x4*)(x + i);
  f32x4 f1 = *(const f32x4*)(x + i + 4);
  short8 t;
  #pragma unroll
  for (int j = 0; j < 4; j++){ t[j] = (short)f2bf(f0[j]); t[4+j] = (short)f2bf(f1[j]); }
  *(short8*)(xb + i) = t;
}

// ---- CSR build: hist -> scan -> scatter ----
__global__ void hist_k(const int* __restrict__ dst, int* __restrict__ hist){
  int e = blockIdx.x*256 + threadIdx.x;
  atomicAdd(&hist[dst[e]], 1);
}

__global__ void scan1_k(const int* __restrict__ hist, int* __restrict__ rs, int* __restrict__ bsum){
  __shared__ int wsum[4];
  int t = threadIdx.x;
  int base = blockIdx.x*1024 + t*4;
  int4 v = *(const int4*)(hist + base);
  int s = v.x + v.y + v.z + v.w;
  int lane = t & 63, w = t >> 6;
  int inc = s;
  #pragma unroll
  for (int o = 1; o < 64; o <<= 1){ int n = __shfl_up(inc, o); if (lane >= o) inc += n; }
  if (lane == 63) wsum[w] = inc;
  __syncthreads();
  int acc = 0;
  for (int i = 0; i < w; i++) acc += wsum[i];
  int ex = acc + inc - s;
  rs[base] = ex; rs[base+1] = ex + v.x; rs[base+2] = ex + v.x + v.y; rs[base+3] = ex + v.x + v.y + v.z;
  if (t == 255) bsum[blockIdx.x] = acc + inc;
}

__global__ void scan2_k(int* bsum){
  int lane = threadIdx.x;
  int v = bsum[lane], inc = v;
  #pragma unroll
  for (int o = 1; o < 64; o <<= 1){ int n = __shfl_up(inc, o); if (lane >= o) inc += n; }
  bsum[lane] = inc - v;
}

__global__ void scan3_k(int* rs, const int* bsum, int* cursor){
  int i = blockIdx.x*256 + threadIdx.x;
  int v = rs[i] + bsum[i >> 10];
  rs[i] = v; cursor[i] = v;
}

// key = byte offset of the (src,sel) row in Y, bit0 = (sel==0) shortcut flag
__global__ void scatter_k(const int* __restrict__ src, const int* __restrict__ dst,
                          const int* __restrict__ sel,
                          int* __restrict__ cursor, int* __restrict__ sorted){
  int e = blockIdx.x*256 + threadIdx.x;
  int d = dst[e];
  int sl = sel[e];
  int pos = atomicAdd(&cursor[d], 1);
  sorted[pos] = src[e]*2560 + sl*256 + (sl == 0 ? 1 : 0);
}

// ---- GEMM: [65536,128]bf16 @ Wt[ncols,128]^T -> C[n][col] bf16 ----
// Block = 4 waves covering 64 rows x 128 cols/nt; wave tile 32x64 (acc=32 VGPR).
// grid.x=1024 -> 4 blocks/CU = 16 waves/CU (R1: 8, R2: VGPR-capped 12 + A-dup).
// All nt per block: B (320 KB) L2-resident is the only duplicated read.
template<int NT>
__global__ __launch_bounds__(256,4) void gemm_k(const unsigned short* __restrict__ A,
                       const unsigned short* __restrict__ Wt,
                       unsigned short* __restrict__ C, int ostride){
  __shared__ unsigned short stg[64*136];    // repack, rows padded to 272B
  int w = threadIdx.x >> 6, lane = threadIdx.x & 63;
  int q = lane >> 4, r = lane & 15;
  int wr = w >> 1, wc = w & 1;              // row-half / col-half of the block tile
  int m0 = blockIdx.x * 64;

  short8 a[2][4];                            // hoisted A-frags: K=128 in regs
  #pragma unroll
  for (int ms = 0; ms < 2; ms++){
    int row = m0 + wr*32 + ms*16 + r;
    #pragma unroll
    for (int kk = 0; kk < 4; kk++)
      a[ms][kk] = *(const short8*)(A + (size_t)row*128 + kk*32 + q*8);
  }

  for (int nt = 0; nt < NT; nt++){
    f32x4 acc[2][4];
    #pragma unroll
    for (int ms = 0; ms < 2; ms++)
      #pragma unroll
      for (int ns = 0; ns < 4; ns++) acc[ms][ns] = (f32x4){0.f,0.f,0.f,0.f};

    #pragma unroll
    for (int kk = 0; kk < 4; kk++){
      short8 b[4];
      #pragma unroll
      for (int ns = 0; ns < 4; ns++){
        const unsigned short* p = Wt + (size_t)(nt*128 + wc*64 + ns*16 + r)*128 + kk*32 + q*8;
        b[ns] = *(const short8*)p;
      }
      #pragma unroll
      for (int ns = 0; ns < 4; ns++)
        #pragma unroll
        for (int ms = 0; ms < 2; ms++)
          acc[ms][ns] = __builtin_amdgcn_mfma_f32_16x16x32_bf16(a[ms][kk], b[ns], acc[ms][ns], 0, 0, 0);
    }

    // repack via LDS: each wave touches only its own 32x64 quadrant -> no barrier
    #pragma unroll
    for (int ms = 0; ms < 2; ms++)
      #pragma unroll
      for (int ns = 0; ns < 4; ns++)
        #pragma unroll
        for (int rr = 0; rr < 4; rr++){
          int lrow = wr*32 + ms*16 + q*4 + rr;
          int lcol = wc*64 + ns*16 + r;
          stg[lrow*136 + lcol] = f2bf(acc[ms][ns][rr]);
        }
    #pragma unroll
    for (int i = 0; i < 4; i++){
      int idx = i*64 + lane;            // 256 chunks of 16B = 32 rows x 128B half-rows
      int row = idx >> 3;
      int within = idx & 7;
      short8 vv = *(const short8*)&stg[(wr*32 + row)*136 + wc*64 + within*8];
      int grow = m0 + wr*32 + row;
      *(short8*)(C + (size_t)grow*ostride + nt*128 + wc*64 + within*8) = vv;
    }
  }
}

// ---- gather layer 1: 4 nodes/wave, 16 lanes/node, 16B/lane loads ----
__global__ void gather1_k(const unsigned short* __restrict__ Y, const int* __restrict__ rs,
                          const int* __restrict__ cur, const int* __restrict__ sorted,
                          const float* __restrict__ bias1, unsigned short* __restrict__ h1){
  int lane = threadIdx.x & 63;
  int g = lane >> 4, r = lane & 15;
  int node = blockIdx.x*16 + (threadIdx.x >> 6)*4 + g;
  int s = rs[node], e = cur[node];
  const char* Yb = (const char*)Y;
  float acc[8];
  #pragma unroll
  for (int j = 0; j < 8; j++) acc[j] = 0.f;
  for (int i = s; i < e; i++){
    int key = sorted[i];
    short8 v = *(const short8*)(Yb + (size_t)(key & ~255) + r*16);
    #pragma unroll
    for (int j = 0; j < 8; j++) acc[j] += bf2f((unsigned short)v[j]);
  }
  f32x4 b0 = *(const f32x4*)(bias1 + r*8);
  f32x4 b1 = *(const f32x4*)(bias1 + r*8 + 4);
  short8 o;
  #pragma unroll
  for (int j = 0; j < 4; j++){
    o[j]   = (short)f2bf(elu1(acc[j]   + b0[j]));
    o[4+j] = (short)f2bf(elu1(acc[4+j] + b1[j]));
  }
  *(short8*)(h1 + (size_t)node*128 + r*8) = o;
}

// ---- gather layer 2 + shortcut + BN2/ELU/BN3/ELU -> fp32 out ----
__global__ void gather2_k(const unsigned short* __restrict__ Y, const int* __restrict__ rs,
                          const int* __restrict__ cur, const int* __restrict__ sorted,
                          const float* __restrict__ bias2, const float* __restrict__ bias3,
                          const float* __restrict__ s3v, float* __restrict__ out){
  int lane = threadIdx.x & 63;
  int g = lane >> 4, r = lane & 15;
  int node = blockIdx.x*16 + (threadIdx.x >> 6)*4 + g;
  int s = rs[node], e = cur[node];
  const char* Yb = (const char*)Y;
  float acc[8], sc[8];
  #pragma unroll
  for (int j = 0; j < 8; j++){ acc[j] = 0.f; sc[j] = 0.f; }
  for (int i = s; i < e; i++){
    int key = sorted[i];
    size_t off = (size_t)(key & ~255);
    short8 v = *(const short8*)(Yb + off + r*16);
    #pragma unroll
    for (int j = 0; j < 8; j++) acc[j] += bf2f((unsigned short)v[j]);
    if (key & 1){                       // sel==0 -> add Y3 shortcut row (off = src*2560)
      short8 u = *(const short8*)(Yb + off + 2304 + r*16);
      #pragma unroll
      for (int j = 0; j < 8; j++) sc[j] += bf2f((unsigned short)u[j]);
    }
  }
  f32x4 o0, o1;
  #pragma unroll
  for (int j = 0; j < 4; j++){
    int c0 = r*8 + j, c1 = r*8 + 4 + j;
    float h0 = elu1(acc[j]   + bias2[c0]);
    float h1v = elu1(acc[4+j] + bias2[c1]);
    o0[j] = elu1(h0*s3v[c0]  + sc[j]   + bias3[c0]);
    o1[j] = elu1(h1v*s3v[c1] + sc[4+j] + bias3[c1]);
  }
  float* po = out + (size_t)node*128 + r*8;
  *(f32x4*)po = o0;
  *(f32x4*)(po + 4) = o1;
}

extern "C" void kernel_launch(void* const* d_in, const int* in_sizes, int n_in,
                              void* d_out, int out_size, void* d_ws, size_t ws_size,
                              hipStream_t stream){
  const float* x   = (const float*)d_in[0];
  const int*   ei  = (const int*)d_in[1];
  const int*   sel = (const int*)d_in[2];
  const float* W1  = (const float*)d_in[3];
  const float* b1  = (const float*)d_in[4];
  const float* g1  = (const float*)d_in[5];
  const float* be1 = (const float*)d_in[6];
  const float* rm1 = (const float*)d_in[7];
  const float* rv1 = (const float*)d_in[8];
  const float* W2  = (const float*)d_in[9];
  const float* b2  = (const float*)d_in[10];
  const float* g2  = (const float*)d_in[11];
  const float* be2 = (const float*)d_in[12];
  const float* rm2 = (const float*)d_in[13];
  const float* rv2 = (const float*)d_in[14];
  const float* W3  = (const float*)d_in[15];
  const float* b3  = (const float*)d_in[16];
  const float* g3  = (const float*)d_in[17];
  const float* be3 = (const float*)d_in[18];
  const float* rm3 = (const float*)d_in[19];
  const float* rv3 = (const float*)d_in[20];

  char* ws = (char*)d_ws;
  unsigned short* Y    = (unsigned short*)(ws);                   // [65536][1280] bf16
  unsigned short* h1   = (unsigned short*)(ws + 167772160);       // [65536][128] bf16; aliased as xb pre-gather1
  unsigned short* Wt1  = (unsigned short*)(ws + 184549376);       // [1280][128] bf16
  unsigned short* Wt2  = (unsigned short*)(ws + 184877056);       // [1152][128] bf16
  float* bias1  = (float*)(ws + 185171968);
  float* bias2  = bias1 + 128;
  float* bias3  = bias1 + 256;
  float* s3v    = bias1 + 384;
  int* hist     = (int*)(ws + 185174016);
  int* rs       = (int*)(ws + 185436160);
  int* cursor   = (int*)(ws + 185698304);
  int* bsum     = (int*)(ws + 185960448);
  int* sorted   = (int*)(ws + 185960704);                         // end: 188,320,000 bytes
  unsigned short* xb = h1;                                        // alias: xb live only until GEMM1 done

  const int* srcp = ei;
  const int* dstp = ei + NEDGE;

  hipMemsetAsync(hist, 0, N_NODES*sizeof(int), stream);
  prep_w<<<1216, 256, 0, stream>>>(W1, W2, W3, g1, rv1, g2, rv2, g3, rv3, Wt1, Wt2);
  prep_bias<<<1, 128, 0, stream>>>(b1,g1,be1,rm1,rv1, b2,g2,be2,rm2,rv2, b3,g3,be3,rm3,rv3,
                                   bias1, bias2, bias3, s3v);
  xcast_k<<<4096, 256, 0, stream>>>(x, xb);
  hist_k<<<NEDGE/256, 256, 0, stream>>>(dstp, hist);
  scan1_k<<<64, 256, 0, stream>>>(hist, rs, bsum);
  scan2_k<<<1, 64, 0, stream>>>(bsum);
  scan3_k<<<256, 256, 0, stream>>>(rs, bsum, cursor);
  scatter_k<<<NEDGE/256, 256, 0, stream>>>(srcp, dstp, sel, cursor, sorted);

  gemm_k<10><<<1024, 256, 0, stream>>>(xb, Wt1, Y, 1280);              // Y1 (9 dirs) + Y3
  gather1_k<<<4096, 256, 0, stream>>>(Y, rs, cursor, sorted, bias1, h1);
  gemm_k<9><<<1024, 256, 0, stream>>>(h1, Wt2, Y, 1280);               // Y2 overwrites dir cols, keeps Y3
  gather2_k<<<4096, 256, 0, stream>>>(Y, rs, cursor, sorted, bias2, bias3, s3v, (float*)d_out);
}